// Round 6
// baseline (196.801 us; speedup 1.0000x reference)
//
#include <hip/hip_runtime.h>
#include <float.h>
#include <math.h>

#define NB 8192      // batch
#define NC 128       // classes
#define NT 64        // time steps
#define ACE_EPS 1e-5f
#define MAGIC 0x5A17C0DEu

// workspace layout:
//   [0,    32KB)   loss[NB]   (float, published via agent-scope atomics)
//   [32KB, 64KB)   flags[NB]  (u32, MAGIC when loss[b] is valid)

// ---------------------------------------------------------------------------
// Single fused kernel. One wave per sample, 4 samples per 256-thread block,
// grid = NB/4 = 2048 blocks. NO LDS in the hot path, NO inter-block deps in
// the main phase.
//   phase 1: streaming argmax over C (32 coalesced float4 loads/lane, 1 KiB
//            per wave-instruction), shuffle combine. [proven 5.2 TB/s core]
//   phase 2: per-wave redundant prefix of lens (int4 reduce over L2-resident
//            32 KB input) -> start offset; no prefix kernel, no sync.
//   phase 3: ballot/popcount loss tail (lane l holds argmax of
//            t = 4*(l&15)+(l>>4), a bijection over t).
//   phase 4: publish loss[b] (atomic, agent) + release flag; block
//            gridDim-1 spin-acquires all flags and does the fixed-order
//            deterministic mean. Poison-safe: flags==0xAA.. forces a real
//            wait; leftover MAGIC from a prior replay only exposes identical
//            values (deterministic), a benign race.
// ---------------------------------------------------------------------------
__global__ __launch_bounds__(256, 8) void ace_one_kernel(
    const float* __restrict__ x, const int* __restrict__ y,
    const int* __restrict__ lens, float* __restrict__ loss,
    unsigned int* __restrict__ flags, float* __restrict__ out) {
  const int wave = threadIdx.x >> 6;
  const int lane = threadIdx.x & 63;
  const int bid = blockIdx.x;
  const int b = bid * 4 + wave;
  const int crow = lane >> 4;

  // ---- phase 1: streaming argmax ----
  const float4* xv = (const float4*)(x + (size_t)b * (NC * NT));
  float mv[4];
  int am[4];
#pragma unroll
  for (int j = 0; j < 4; ++j) { mv[j] = -FLT_MAX; am[j] = 0; }

#pragma unroll 8
  for (int cc = 0; cc < 32; ++cc) {
    const int c = cc * 4 + crow;
    float4 v = xv[cc * 64 + lane];
    float vv[4] = {v.x, v.y, v.z, v.w};
#pragma unroll
    for (int j = 0; j < 4; ++j) {
      if (vv[j] > mv[j]) { mv[j] = vv[j]; am[j] = c; }   // strict > : first max
    }
  }
#pragma unroll
  for (int j = 0; j < 4; ++j) {
#pragma unroll
    for (int off = 16; off < 64; off <<= 1) {
      float om = __shfl_xor(mv[j], off, 64);
      int oa = __shfl_xor(am[j], off, 64);
      if (om > mv[j] || (om == mv[j] && oa < am[j])) { mv[j] = om; am[j] = oa; }
    }
  }
  int my_am = am[0];
  if (crow == 1) my_am = am[1];
  if (crow == 2) my_am = am[2];
  if (crow == 3) my_am = am[3];

  // ---- phase 2: per-wave prefix of lens (redundant, L2-resident input) ----
  const int4* l4 = (const int4*)lens;      // lens[4i..4i+3]
  int ps = 0;
  for (int i = lane; i < bid; i += 64) {   // sum lens[0 .. 4*bid)
    int4 t = l4[i];
    ps += t.x + t.y + t.z + t.w;
  }
#pragma unroll
  for (int off = 1; off < 64; off <<= 1) ps += __shfl_xor(ps, off, 64);
  int e = (lane < wave) ? lens[bid * 4 + lane] : 0;      // lens[4bid .. b)
  const int start = ps + __shfl(e, 0, 64) + __shfl(e, 1, 64) + __shfl(e, 2, 64);
  const int len = lens[b];

  // ---- phase 3: ballot/popcount loss tail ----
  const int yv = (lane < len) ? y[start + lane] : -1;

  int ns = 0;
  for (int i = 0; i < len; ++i) {
    const int c = __shfl(yv, i, 64);
    const unsigned long long baly = __ballot(lane < len && yv == c);
    const int nkc = __popcll(__ballot(my_am == c));
    if ((int)__ffsll(baly) - 1 == i) ns += nkc;   // uniform: first occurrence
  }
  const float inv_ns = (ns > 0) ? (1.0f / (float)ns) : 0.0f;
  const float inv_ys = 1.0f / (float)len;         // y_sum == len
  float a = 0.0f;
  for (int i = 0; i < len; ++i) {
    const int c = __shfl(yv, i, 64);
    const unsigned long long baly = __ballot(lane < len && yv == c);
    if ((int)__ffsll(baly) - 1 == i) {            // uniform branch
      const int nkc = __popcll(__ballot(my_am == c));
      const int ykc = __popcll(baly);
      const float np = (ns == 0) ? ACE_EPS : fmaxf((float)nkc * inv_ns, ACE_EPS);
      a -= np * logf((float)ykc * inv_ys);
    }
  }

  // ---- phase 4: publish; last block reduces ----
  if (lane == 0) {
    __hip_atomic_store((unsigned int*)&loss[b], __float_as_uint(a),
                       __ATOMIC_RELAXED, __HIP_MEMORY_SCOPE_AGENT);
    __hip_atomic_store(&flags[b], MAGIC,
                       __ATOMIC_RELEASE, __HIP_MEMORY_SCOPE_AGENT);
  }

  if (bid == (int)gridDim.x - 1) {
    // spin-acquire all sample flags (safe: never waits on a later block)
    for (int i = threadIdx.x; i < NB; i += 256) {
      while (__hip_atomic_load(&flags[i], __ATOMIC_ACQUIRE,
                               __HIP_MEMORY_SCOPE_AGENT) != MAGIC)
        __builtin_amdgcn_s_sleep(1);
    }
    __syncthreads();
    // deterministic fixed-order mean
    __shared__ float s[256];
    float acc = 0.0f;
    for (int i = threadIdx.x; i < NB; i += 256) {
      unsigned int u = __hip_atomic_load((unsigned int*)&loss[i],
                                         __ATOMIC_RELAXED,
                                         __HIP_MEMORY_SCOPE_AGENT);
      acc += __uint_as_float(u);
    }
    s[threadIdx.x] = acc;
    __syncthreads();
    for (int off = 128; off > 0; off >>= 1) {
      if ((int)threadIdx.x < off) s[threadIdx.x] += s[threadIdx.x + off];
      __syncthreads();
    }
    if (threadIdx.x == 0) out[0] = s[0] / (float)NB;
  }
}

extern "C" void kernel_launch(void* const* d_in, const int* in_sizes, int n_in,
                              void* d_out, int out_size, void* d_ws, size_t ws_size,
                              hipStream_t stream) {
  const float* x = (const float*)d_in[0];          // [B, C, T] f32
  const int* y = (const int*)d_in[1];              // [B*L] i32
  const int* lens = (const int*)d_in[2];           // [B] i32
  float* out = (float*)d_out;                      // scalar f32

  float* loss = (float*)d_ws;                                    // 32 KB
  unsigned int* flags = (unsigned int*)((char*)d_ws + 32 * 1024);// 32 KB

  ace_one_kernel<<<NB / 4, 256, 0, stream>>>(x, y, lens, loss, flags, out);
}

// Round 7
// 71.865 us; speedup vs baseline: 2.7385x; 2.7385x over previous
//
#include <hip/hip_runtime.h>
#include <float.h>
#include <math.h>

#define NB 8192      // batch
#define NC 128       // classes
#define NT 64        // time steps
#define ACE_EPS 1e-5f

// workspace layout:
//   [0, 32KB)   loss[NB]  (float)

// ---------------------------------------------------------------------------
// A) fused streaming argmax + inline prefix + ACE loss tail.
//    One wave per sample, 4 samples per 256-thread block. No LDS, no atomics.
//    Hot loop is a HAND-PIPELINED 8-stage rotating float4 buffer, fully
//    unrolled: dataflow forces 8 loads in flight (32 data VGPRs) so the
//    allocator cannot serialize the stream (R2/R6 failure mode).
//    Lane mapping: tg=lane&15 (t=4tg..4tg+3), crow=lane>>4 (c=4*cc+crow);
//    wave reads 1 KiB contiguous per load instruction.
// ---------------------------------------------------------------------------
__global__ __launch_bounds__(256, 8) void ace_fused_kernel(
    const float* __restrict__ x, const int* __restrict__ y,
    const int* __restrict__ lens, float* __restrict__ loss_out) {
  const int wave = threadIdx.x >> 6;
  const int lane = threadIdx.x & 63;
  const int bid = blockIdx.x;
  const int b = bid * 4 + wave;
  const int crow = lane >> 4;

  const float4* xv = (const float4*)(x + (size_t)b * (NC * NT)) + lane;

  float mv[4];
  int am[4];
#pragma unroll
  for (int j = 0; j < 4; ++j) { mv[j] = -FLT_MAX; am[j] = 0; }

  // ---- 8-stage software pipeline over 32 float4 loads ----
  float4 p0 = xv[0 * 64], p1 = xv[1 * 64], p2 = xv[2 * 64], p3 = xv[3 * 64];
  float4 p4 = xv[4 * 64], p5 = xv[5 * 64], p6 = xv[6 * 64], p7 = xv[7 * 64];

#define CONSUME(P, CC)                                                       \
  {                                                                          \
    const int c = (CC) * 4 + crow;                                           \
    if (P.x > mv[0]) { mv[0] = P.x; am[0] = c; }                             \
    if (P.y > mv[1]) { mv[1] = P.y; am[1] = c; }                             \
    if (P.z > mv[2]) { mv[2] = P.z; am[2] = c; }                             \
    if (P.w > mv[3]) { mv[3] = P.w; am[3] = c; }                             \
  }

#pragma unroll
  for (int base = 0; base < 32; base += 8) {
    CONSUME(p0, base + 0); if (base + 8 < 32) p0 = xv[(base + 8) * 64];
    CONSUME(p1, base + 1); if (base + 9 < 32) p1 = xv[(base + 9) * 64];
    CONSUME(p2, base + 2); if (base + 10 < 32) p2 = xv[(base + 10) * 64];
    CONSUME(p3, base + 3); if (base + 11 < 32) p3 = xv[(base + 11) * 64];
    CONSUME(p4, base + 4); if (base + 12 < 32) p4 = xv[(base + 12) * 64];
    CONSUME(p5, base + 5); if (base + 13 < 32) p5 = xv[(base + 13) * 64];
    CONSUME(p6, base + 6); if (base + 14 < 32) p6 = xv[(base + 14) * 64];
    CONSUME(p7, base + 7); if (base + 15 < 32) p7 = xv[(base + 15) * 64];
  }
#undef CONSUME

  // combine across the 4 lanes (crow dim) sharing one t-group; min idx on tie
#pragma unroll
  for (int j = 0; j < 4; ++j) {
#pragma unroll
    for (int off = 16; off < 64; off <<= 1) {
      float om = __shfl_xor(mv[j], off, 64);
      int oa = __shfl_xor(am[j], off, 64);
      if (om > mv[j] || (om == mv[j] && oa < am[j])) { mv[j] = om; am[j] = oa; }
    }
  }
  int my_am = am[0];
  if (crow == 1) my_am = am[1];
  if (crow == 2) my_am = am[2];
  if (crow == 3) my_am = am[3];

  // ---- inline per-wave prefix of lens (redundant, L2-resident 32 KB) ----
  const int4* l4 = (const int4*)lens;
  int ps = 0;
  for (int i = lane; i < bid; i += 64) {   // sum lens[0 .. 4*bid)
    int4 t = l4[i];
    ps += t.x + t.y + t.z + t.w;
  }
#pragma unroll
  for (int off = 1; off < 64; off <<= 1) ps += __shfl_xor(ps, off, 64);
  int e = (lane < wave) ? lens[bid * 4 + lane] : 0;      // lens[4bid .. b)
  const int start = ps + __shfl(e, 0, 64) + __shfl(e, 1, 64) + __shfl(e, 2, 64);
  const int len = lens[b];

  // ---- ballot/popcount loss tail (lane l owns t = 4*(l&15)+(l>>4)) ----
  const int yv = (lane < len) ? y[start + lane] : -1;

  int ns = 0;
  for (int i = 0; i < len; ++i) {
    const int c = __shfl(yv, i, 64);
    const unsigned long long baly = __ballot(lane < len && yv == c);
    const int nkc = __popcll(__ballot(my_am == c));
    if ((int)__ffsll(baly) - 1 == i) ns += nkc;   // uniform: first occurrence
  }
  const float inv_ns = (ns > 0) ? (1.0f / (float)ns) : 0.0f;
  const float inv_ys = 1.0f / (float)len;         // y_sum == len
  float a = 0.0f;
  for (int i = 0; i < len; ++i) {
    const int c = __shfl(yv, i, 64);
    const unsigned long long baly = __ballot(lane < len && yv == c);
    if ((int)__ffsll(baly) - 1 == i) {            // uniform branch
      const int nkc = __popcll(__ballot(my_am == c));
      const int ykc = __popcll(baly);
      const float np = (ns == 0) ? ACE_EPS : fmaxf((float)nkc * inv_ns, ACE_EPS);
      a -= np * logf((float)ykc * inv_ys);
    }
  }
  if (lane == 0) loss_out[b] = a;
}

// ---------------------------------------------------------------------------
// C) deterministic mean over B per-sample losses — single 1024-thread block
// ---------------------------------------------------------------------------
__global__ void reduce_kernel(const float* __restrict__ loss,
                              float* __restrict__ out) {
  __shared__ float s[1024];
  float a = 0.0f;
  for (int i = threadIdx.x; i < NB; i += 1024) a += loss[i];
  s[threadIdx.x] = a;
  __syncthreads();
  for (int off = 512; off > 0; off >>= 1) {
    if ((int)threadIdx.x < off) s[threadIdx.x] += s[threadIdx.x + off];
    __syncthreads();
  }
  if (threadIdx.x == 0) out[0] = s[0] / (float)NB;
}

extern "C" void kernel_launch(void* const* d_in, const int* in_sizes, int n_in,
                              void* d_out, int out_size, void* d_ws, size_t ws_size,
                              hipStream_t stream) {
  const float* x = (const float*)d_in[0];          // [B, C, T] f32
  const int* y = (const int*)d_in[1];              // [B*L] i32
  const int* lens = (const int*)d_in[2];           // [B] i32
  float* out = (float*)d_out;                      // scalar f32

  float* loss = (float*)d_ws;                      // 32 KB

  ace_fused_kernel<<<NB / 4, 256, 0, stream>>>(x, y, lens, loss);
  reduce_kernel<<<1, 1024, 0, stream>>>(loss, out);
}